// Round 5
// baseline (229.023 us; speedup 1.0000x reference)
//
#include <hip/hip_runtime.h>
#include <math.h>

typedef unsigned short u16;
typedef unsigned int u32;
typedef __attribute__((ext_vector_type(4))) float f32x4;
typedef __attribute__((ext_vector_type(8))) short bf16x8;

#define B_ 2
#define T_ 2048
#define H_ 16
#define HID 1024
#define NQKV 3072
#define M_ 4096
#define SCALE_Q 0.18033688011112042f /* 0.125 * log2(e): softmax done in exp2 domain */

__device__ __forceinline__ u16 f2bf(float f) {
  union { float f; unsigned u; } v; v.f = f;
  unsigned r = v.u + 0x7FFFu + ((v.u >> 16) & 1u);
  return (u16)(r >> 16);
}
__device__ __forceinline__ float bf2f(u16 u) {
  union { unsigned u; float f; } v; v.u = ((unsigned)u) << 16; return v.f;
}
__device__ __forceinline__ u32 cvt_pk_bf16(float lo, float hi) {
  u32 r;
  asm("v_cvt_pk_bf16_f32 %0, %1, %2" : "=v"(r) : "v"(lo), "v"(hi));
  return r;
}
__device__ __forceinline__ float fexp2(float x) { return __builtin_amdgcn_exp2f(x); }

// async global->LDS, 16B per lane; LDS dest = wave-uniform base + lane*16
__device__ __forceinline__ void gload16(const void* g, void* l) {
  __builtin_amdgcn_global_load_lds((const __attribute__((address_space(1))) void*)g,
                                   (__attribute__((address_space(3))) void*)l, 16, 0, 0);
}

// ---------------- prep: rope table + 3x fp32->bf16 convert, fused ----------------
__global__ void prep(const float* __restrict__ x, const float* __restrict__ qkv_w,
                     const float* __restrict__ out_w, u16* __restrict__ xb,
                     u16* __restrict__ wqkv, u16* __restrict__ wout, float* __restrict__ tab) {
  int bid = blockIdx.x;
  if (bid < 128) {  // rope table: tab[t*16+f] = {cos, sin}
    int i = bid * 256 + threadIdx.x;
    int tpos = i >> 4, f = i & 15;
    float ang = (float)tpos * exp2f(-(float)f * 0.83048202372184058696f);
    float s, c;
    sincosf(ang, &s, &c);
    tab[i * 2] = c;
    tab[i * 2 + 1] = s;
    return;
  }
  bid -= 128;
  const float* in;
  u16* out;
  if (bid < 4096) { in = x; out = xb; }
  else if (bid < 7168) { bid -= 4096; in = qkv_w; out = wqkv; }
  else { bid -= 7168; in = out_w; out = wout; }
  int i = bid * 256 + threadIdx.x;
  float4 v = ((const float4*)in)[i];
  uint2 o;
  o.x = (unsigned)f2bf(v.x) | ((unsigned)f2bf(v.y) << 16);
  o.y = (unsigned)f2bf(v.z) | ((unsigned)f2bf(v.w) << 16);
  ((uint2*)out)[i] = o;
}

// ---------------- NT GEMM, dbuf-prefetch: C = A.Bt^T + bias ----------------
// A:[M][K], Bt:[N][K] bf16. Tile BM x 128, BK=32, 4 waves as WROWS x (4/WROWS).
template<int BM, int WROWS, int OUT_BF16>
__global__ __launch_bounds__(256, 2) void gemm_nt(const u16* __restrict__ A,
    const u16* __restrict__ Bt, const float* __restrict__ bias,
    void* __restrict__ outp, int N, int K)
{
  constexpr int WCOLS = 4 / WROWS;
  constexpr int MI = BM / WROWS / 16;
  constexpr int NI = 128 / WCOLS / 16;
  constexpr int GA = BM / 16 / 4;   // A 1KB-slab gloads per wave
  constexpr int GB = 128 / 16 / 4;  // B slab gloads per wave
  __shared__ u16 lsA[2][BM * 32];
  __shared__ u16 lsB[2][128 * 32];
  const int t = threadIdx.x;
  const int l = t & 63, w = t >> 6;
  const int wm = (w / WCOLS) * (BM / WROWS);
  const int wn = (w % WCOLS) * (128 / WCOLS);
  const int lr = l & 15, lg = l >> 4;
  const long bm = (long)blockIdx.y * BM, bn = (long)blockIdx.x * 128;

  f32x4 acc[MI][NI];
#pragma unroll
  for (int i = 0; i < MI; i++)
#pragma unroll
    for (int j = 0; j < NI; j++) acc[i][j] = (f32x4){0.f, 0.f, 0.f, 0.f};

  // staging: slab = 16 rows x 32 k = 1KB = one wave-wide gload16
  const int srow = l >> 2, sko = (l & 3) * 8;
  const u16* Ab = A + (bm + srow) * (long)K + sko;
  const u16* Bb = Bt + (bn + srow) * (long)K + sko;

  auto stage = [&](int buf, int k0) {
#pragma unroll
    for (int g = 0; g < GA; g++)
      gload16(Ab + (long)((w * GA + g) * 16) * K + k0, &lsA[buf][(w * GA + g) * 512]);
#pragma unroll
    for (int g = 0; g < GB; g++)
      gload16(Bb + (long)((w * GB + g) * 16) * K + k0, &lsB[buf][(w * GB + g) * 512]);
  };

  stage(0, 0);
  __syncthreads();  // drains vmcnt(0): tile 0 landed
  int cur = 0;
  for (int k0 = 0; k0 < K; k0 += 32) {
    if (k0 + 32 < K) stage(cur ^ 1, k0 + 32);  // prefetch overlaps compute below
    bf16x8 af[MI], bfv[NI];
#pragma unroll
    for (int mi = 0; mi < MI; mi++)
      af[mi] = *(const bf16x8*)&lsA[cur][(wm + mi * 16 + lr) * 32 + lg * 8];
#pragma unroll
    for (int ni = 0; ni < NI; ni++)
      bfv[ni] = *(const bf16x8*)&lsB[cur][(wn + ni * 16 + lr) * 32 + lg * 8];
    __builtin_amdgcn_s_setprio(1);
#pragma unroll
    for (int mi = 0; mi < MI; mi++)
#pragma unroll
      for (int ni = 0; ni < NI; ni++)
        acc[mi][ni] = __builtin_amdgcn_mfma_f32_16x16x32_bf16(af[mi], bfv[ni], acc[mi][ni], 0, 0, 0);
    __builtin_amdgcn_s_setprio(0);
    __syncthreads();  // vmcnt(0)+barrier: prefetch landed, reads done before overwrite
    cur ^= 1;
  }
#pragma unroll
  for (int mi = 0; mi < MI; mi++)
#pragma unroll
    for (int ni = 0; ni < NI; ni++) {
      long row = bm + wm + mi * 16 + lg * 4;
      long col = bn + wn + ni * 16 + lr;
      float bv = bias[col];
#pragma unroll
      for (int r = 0; r < 4; r++) {
        float v = acc[mi][ni][r] + bv;
        if (OUT_BF16) ((u16*)outp)[(row + r) * (long)N + col] = f2bf(v);
        else          ((float*)outp)[(row + r) * (long)N + col] = v;
      }
    }
}

// ---------------- post_qkv: RoPE(q,k) + V transpose, fused ----------------
// blocks [0,256): rope; blocks [256,1280): v_trans
__global__ __launch_bounds__(256) void post_qkv(const u16* __restrict__ qkv,
    const float* __restrict__ tab, u16* __restrict__ Q, u16* __restrict__ K,
    u16* __restrict__ Vt) {
  __shared__ u16 ls[64 * 72];
  const int bid = blockIdx.x;
  if (bid < 256) {
    int idx = bid * 256 + threadIdx.x;  // one thread per (m, h)
    int h = idx & 15;
    int m = idx >> 4;
    int tpos = m & (T_ - 1);
    int b = m >> 11;
    const u16* qr = qkv + (long)m * NQKV + h * 64;
    alignas(16) u16 qv[64];
    alignas(16) u16 kv[64];
#pragma unroll
    for (int c = 0; c < 8; c++) {
      *(int4*)&qv[c * 8] = *(const int4*)&qr[c * 8];
      *(int4*)&kv[c * 8] = *(const int4*)&qr[1024 + c * 8];
    }
#pragma unroll
    for (int i = 0; i < 16; i++) {
      float c = tab[(tpos * 16 + i) * 2];
      float s = tab[(tpos * 16 + i) * 2 + 1];
      float q1 = bf2f(qv[2 * i]), q2 = bf2f(qv[2 * i + 1]);
      qv[2 * i]     = f2bf((q1 * c - q2 * s) * SCALE_Q);
      qv[2 * i + 1] = f2bf((q1 * s + q2 * c) * SCALE_Q);
      float k1 = bf2f(kv[2 * i]), k2 = bf2f(kv[2 * i + 1]);
      kv[2 * i]     = f2bf(k1 * c - k2 * s);
      kv[2 * i + 1] = f2bf(k1 * s + k2 * c);
    }
#pragma unroll
    for (int j = 32; j < 64; j++) qv[j] = f2bf(bf2f(qv[j]) * SCALE_Q);
    long ob = ((long)(b * 16 + h) * T_ + tpos) * 64;
#pragma unroll
    for (int c = 0; c < 8; c++) {
      *(int4*)&Q[ob + c * 8] = *(int4*)&qv[c * 8];
      *(int4*)&K[ob + c * 8] = *(int4*)&kv[c * 8];
    }
  } else {
    int id2 = bid - 256;
    int tt = id2 & 31, bh = id2 >> 5;
    int b = bh >> 4, h = bh & 15;
    int t = threadIdx.x;
    for (int c = t; c < 512; c += 256) {
      int row = c >> 3, off = (c & 7) * 8;
      *(int4*)&ls[row * 72 + off] =
          *(const int4*)&qkv[((long)(b * T_ + tt * 64 + row)) * NQKV + 2048 + h * 64 + off];
    }
    __syncthreads();
    for (int c = t; c < 512; c += 256) {
      int d = c >> 3, toff = (c & 7) * 8;
      alignas(16) u16 tmp[8];
#pragma unroll
      for (int j = 0; j < 8; j++) tmp[j] = ls[(toff + j) * 72 + d];
      *(int4*)&Vt[((long)(bh * 64 + d)) * T_ + tt * 64 + toff] = *(int4*)tmp;
    }
  }
}

// ---------------- causal flash attention, swapped-QK^T, 32 q-rows/wave ----------------
// 512 blocks (heavy strips first), 4 waves; wave w owns q-rows [qs*128+w*32, +32)
// as two 16-row groups qg. K/V frags read once from LDS feed both qg (2x reuse).
__global__ __launch_bounds__(256, 3) void fattn(const u16* __restrict__ Q, const u16* __restrict__ Kp,
                                                const u16* __restrict__ V, u16* __restrict__ O) {
  const int id = blockIdx.x;
  const int qs = 15 - (id >> 5);  // heavy strips dispatched first
  const int bh = id & 31;
  __shared__ u16 lsK[2][64 * 64];  // [krow][d], XOR swizzle: u16 chunk ^= (row&7)
  __shared__ u16 lsV[2][64 * 64];  // [d][k], same swizzle
  __shared__ u32 lsP[4][32 * 36];  // per-wave P: 32 q-rows x 32 dwords (pad 36)
  const int t = threadIdx.x, l = t & 63, w = t >> 6;
  const int lr = l & 15, lg = l >> 4;
  const u16* Qb = Q + (long)bh * T_ * 64;
  const u16* Kb = Kp + (long)bh * T_ * 64;
  const u16* Vb = V + (long)bh * 64 * T_;
  u32* lsPw = lsP[w];
  const int qbase = qs * 128 + w * 32;  // wave's first q-row

  bf16x8 aq[2][2];  // [qg][ks]: Q B-frags (pre-scaled by 0.125*log2e)
#pragma unroll
  for (int qg = 0; qg < 2; qg++)
#pragma unroll
    for (int ks = 0; ks < 2; ks++)
      aq[qg][ks] = *(const bf16x8*)&Qb[((long)(qbase + qg * 16 + lr)) * 64 + ks * 32 + lg * 8];

  f32x4 o[2][4];
#pragma unroll
  for (int qg = 0; qg < 2; qg++)
#pragma unroll
    for (int di = 0; di < 4; di++) o[qg][di] = (f32x4){0.f, 0.f, 0.f, 0.f};
  float mrow[2] = {-1e30f, -1e30f}, lrow[2] = {0.f, 0.f};

  // staging: slab = 8 rows x 128B; wave w stages slabs {2w,2w+1} of K and V.
  // pre-swizzled global source (m173): LDS chunk c holds src chunk c^(row&7).
  const int srow = l >> 3;
  const int scx = ((l & 7) ^ srow) * 8;
  const long kgo0 = (long)(16 * w + srow) * 64 + scx;
  const long kgo1 = (long)(16 * w + 8 + srow) * 64 + scx;
  const long vgo0 = (long)(16 * w + srow) * T_ + scx;
  const long vgo1 = (long)(16 * w + 8 + srow) * T_ + scx;

  gload16(Kb + kgo0, &lsK[0][(2 * w) * 512]);
  gload16(Kb + kgo1, &lsK[0][(2 * w + 1) * 512]);
  gload16(Vb + vgo0, &lsV[0][(2 * w) * 512]);
  gload16(Vb + vgo1, &lsV[0][(2 * w + 1) * 512]);
  __syncthreads();  // vmcnt(0) drain: tile 0 ready

  int cur = 0;
  const int ktmax = 2 * qs + 1;
  for (int kt = 0; kt <= ktmax; kt++) {
    if (kt < ktmax) {  // prefetch next tile; lands by the end-of-iter barrier
      const u16* kp = Kb + (kt + 1) * 4096;
      const u16* vp = Vb + (kt + 1) * 64;
      gload16(kp + kgo0, &lsK[cur ^ 1][(2 * w) * 512]);
      gload16(kp + kgo1, &lsK[cur ^ 1][(2 * w + 1) * 512]);
      gload16(vp + vgo0, &lsV[cur ^ 1][(2 * w) * 512]);
      gload16(vp + vgo1, &lsV[cur ^ 1][(2 * w + 1) * 512]);
    }
    const int kbase = kt * 64;
    if (kbase <= qbase + 31) {  // tile has unmasked rows for this wave
      // S^T = K . Q^T : each kf read feeds both qg back-to-back
      f32x4 s[2][4];
#pragma unroll
      for (int qg = 0; qg < 2; qg++)
#pragma unroll
        for (int ji = 0; ji < 4; ji++) s[qg][ji] = (f32x4){0.f, 0.f, 0.f, 0.f};
      __builtin_amdgcn_s_setprio(1);
#pragma unroll
      for (int ks = 0; ks < 2; ks++)
#pragma unroll
        for (int ji = 0; ji < 4; ji++) {
          int row = ji * 16 + lr;
          bf16x8 kf = *(const bf16x8*)&lsK[cur][row * 64 + ((ks * 32 + lg * 8) ^ ((row & 7) * 8))];
          s[0][ji] = __builtin_amdgcn_mfma_f32_16x16x32_bf16(kf, aq[0][ks], s[0][ji], 0, 0, 0);
          s[1][ji] = __builtin_amdgcn_mfma_f32_16x16x32_bf16(kf, aq[1][ks], s[1][ji], 0, 0, 0);
        }
      __builtin_amdgcn_s_setprio(0);

#pragma unroll
      for (int qg = 0; qg < 2; qg++) {
        const int qg_q = qbase + qg * 16 + lr;  // this lane's q for group qg
        if (kbase + 63 > qbase + qg * 16) {     // partially/fully masked for qg
#pragma unroll
          for (int ji = 0; ji < 4; ji++)
#pragma unroll
            for (int r = 0; r < 4; r++)
              if (kbase + ji * 16 + lg * 4 + r > qg_q) s[qg][ji][r] = -1e30f;
        }

        // max: 16 in-lane tree + 2 shfl (4 lanes share a q-column)
        float m01 = fmaxf(fmaxf(s[qg][0][0], s[qg][0][1]), fmaxf(s[qg][0][2], s[qg][0][3]));
        float m23 = fmaxf(fmaxf(s[qg][1][0], s[qg][1][1]), fmaxf(s[qg][1][2], s[qg][1][3]));
        float m45 = fmaxf(fmaxf(s[qg][2][0], s[qg][2][1]), fmaxf(s[qg][2][2], s[qg][2][3]));
        float m67 = fmaxf(fmaxf(s[qg][3][0], s[qg][3][1]), fmaxf(s[qg][3][2], s[qg][3][3]));
        float mx = fmaxf(fmaxf(m01, m23), fmaxf(m45, m67));
        mx = fmaxf(mx, __shfl_xor(mx, 16, 64));
        mx = fmaxf(mx, __shfl_xor(mx, 32, 64));

        if (__any(mx - mrow[qg] > 8.f)) {  // defer-max (T13)
          float newm = fmaxf(mrow[qg], mx);
          float sf = fexp2(mrow[qg] - newm);
          mrow[qg] = newm;
          lrow[qg] *= sf;
#pragma unroll
          for (int r = 0; r < 4; r++) {
            float sfb = __shfl(sf, lg * 4 + r, 64);
#pragma unroll
            for (int di = 0; di < 4; di++) o[qg][di][r] *= sfb;
          }
        }

        float p[16];
        u32 pd[8];
#pragma unroll
        for (int ji = 0; ji < 4; ji++)
#pragma unroll
          for (int r = 0; r < 4; r++) p[ji * 4 + r] = fexp2(s[qg][ji][r] - mrow[qg]);
#pragma unroll
        for (int jj = 0; jj < 8; jj++) pd[jj] = cvt_pk_bf16(p[2 * jj], p[2 * jj + 1]);
        float rs;
        {
          float a0 = (p[0] + p[1]) + (p[2] + p[3]);
          float a1 = (p[4] + p[5]) + (p[6] + p[7]);
          float a2 = (p[8] + p[9]) + (p[10] + p[11]);
          float a3 = (p[12] + p[13]) + (p[14] + p[15]);
          rs = (a0 + a1) + (a2 + a3);
        }
        rs += __shfl_xor(rs, 16, 64);
        rs += __shfl_xor(rs, 32, 64);
        lrow[qg] += rs;

        // P -> per-wave LDS rows [qg*16+lr]
#pragma unroll
        for (int ji = 0; ji < 4; ji++)
          *(uint2*)&lsPw[(qg * 16 + lr) * 36 + ji * 8 + lg * 2] = make_uint2(pd[2 * ji], pd[2 * ji + 1]);
      }

      // PV: each vb read feeds both qg
      __builtin_amdgcn_s_setprio(1);
#pragma unroll
      for (int js = 0; js < 2; js++) {
        bf16x8 pa0 = *(const bf16x8*)&lsPw[lr * 36 + js * 16 + lg * 4];
        bf16x8 pa1 = *(const bf16x8*)&lsPw[(16 + lr) * 36 + js * 16 + lg * 4];
#pragma unroll
        for (int di = 0; di < 4; di++) {
          int drow = di * 16 + lr;
          bf16x8 vb = *(const bf16x8*)&lsV[cur][drow * 64 + ((js * 32 + lg * 8) ^ ((drow & 7) * 8))];
          o[0][di] = __builtin_amdgcn_mfma_f32_16x16x32_bf16(pa0, vb, o[0][di], 0, 0, 0);
          o[1][di] = __builtin_amdgcn_mfma_f32_16x16x32_bf16(pa1, vb, o[1][di], 0, 0, 0);
        }
      }
      __builtin_amdgcn_s_setprio(0);
    }

    if (kt < ktmax) __syncthreads();  // drain prefetch + guard buffer reuse
    cur ^= 1;
  }

  const int b = bh >> 4, h = bh & 15;
#pragma unroll
  for (int qg = 0; qg < 2; qg++) {
    float inv = 1.f / lrow[qg];
#pragma unroll
    for (int r = 0; r < 4; r++) {
      float invb = __shfl(inv, lg * 4 + r, 64);
#pragma unroll
      for (int di = 0; di < 4; di++) {
        long rowt = (long)(b * T_ + qbase + qg * 16 + lg * 4 + r);
        O[rowt * 1024 + h * 64 + di * 16 + lr] = f2bf(o[qg][di][r] * invb);
      }
    }
  }
}

extern "C" void kernel_launch(void* const* d_in, const int* in_sizes, int n_in,
                              void* d_out, int out_size, void* d_ws, size_t ws_size,
                              hipStream_t stream) {
  (void)in_sizes; (void)n_in; (void)out_size; (void)ws_size;
  const float* x     = (const float*)d_in[0];
  // d_in[1] = mask: deterministic causal triu — applied analytically, not read.
  const float* qkv_w = (const float*)d_in[2];
  const float* qkv_b = (const float*)d_in[3];
  const float* out_w = (const float*)d_in[4];
  const float* out_b = (const float*)d_in[5];
  char* ws = (char*)d_ws;
  size_t off = 0;
  auto alloc = [&](size_t n) { void* p = ws + off; off += (n + 255) & ~(size_t)255; return p; };
  u16*   xb    = (u16*)alloc((size_t)M_ * HID * 2);
  u16*   wqkv  = (u16*)alloc((size_t)NQKV * HID * 2);
  u16*   wout  = (u16*)alloc((size_t)HID * HID * 2);
  u16*   qkvb  = (u16*)alloc((size_t)M_ * NQKV * 2);
  u16*   Qb    = (u16*)alloc((size_t)M_ * HID * 2);
  u16*   Kb    = (u16*)alloc((size_t)M_ * HID * 2);
  u16*   Vtb   = (u16*)alloc((size_t)M_ * HID * 2);
  u16*   attnb = (u16*)alloc((size_t)M_ * HID * 2);
  float* tab   = (float*)alloc((size_t)T_ * 16 * 2 * 4);

  prep<<<8320, 256, 0, stream>>>(x, qkv_w, out_w, xb, wqkv, wout, tab);
  gemm_nt<256, 2, 1><<<dim3(NQKV / 128, M_ / 256), 256, 0, stream>>>(xb, wqkv, qkv_b, qkvb, NQKV, HID);
  post_qkv<<<1280, 256, 0, stream>>>(qkvb, tab, Qb, Kb, Vtb);
  fattn<<<512, 256, 0, stream>>>(Qb, Kb, Vtb, attnb);
  gemm_nt<64, 1, 0><<<dim3(HID / 128, M_ / 64), 256, 0, stream>>>(attnb, wout, out_b, (float*)d_out, HID, HID);
}

// Round 6
// 194.328 us; speedup vs baseline: 1.1785x; 1.1785x over previous
//
#include <hip/hip_runtime.h>
#include <math.h>

typedef unsigned short u16;
typedef unsigned int u32;
typedef __attribute__((ext_vector_type(4))) float f32x4;
typedef __attribute__((ext_vector_type(8))) short bf16x8;

#define B_ 2
#define T_ 2048
#define H_ 16
#define HID 1024
#define NQKV 3072
#define M_ 4096
#define SCALE_Q 0.18033688011112042f /* 0.125 * log2(e): softmax done in exp2 domain */

__device__ __forceinline__ u16 f2bf(float f) {
  union { float f; unsigned u; } v; v.f = f;
  unsigned r = v.u + 0x7FFFu + ((v.u >> 16) & 1u);
  return (u16)(r >> 16);
}
__device__ __forceinline__ float bf2f(u16 u) {
  union { unsigned u; float f; } v; v.u = ((unsigned)u) << 16; return v.f;
}
__device__ __forceinline__ u32 cvt_pk_bf16(float lo, float hi) {
  u32 r;
  asm("v_cvt_pk_bf16_f32 %0, %1, %2" : "=v"(r) : "v"(lo), "v"(hi));
  return r;
}
__device__ __forceinline__ float fexp2(float x) { return __builtin_amdgcn_exp2f(x); }

// async global->LDS, 16B per lane; LDS dest = wave-uniform base + lane*16
__device__ __forceinline__ void gload16(const void* g, void* l) {
  __builtin_amdgcn_global_load_lds((const __attribute__((address_space(1))) void*)g,
                                   (__attribute__((address_space(3))) void*)l, 16, 0, 0);
}

// ---------------- prep: rope table + 3x fp32->bf16 convert, fused ----------------
__global__ void prep(const float* __restrict__ x, const float* __restrict__ qkv_w,
                     const float* __restrict__ out_w, u16* __restrict__ xb,
                     u16* __restrict__ wqkv, u16* __restrict__ wout, float* __restrict__ tab) {
  int bid = blockIdx.x;
  if (bid < 128) {  // rope table: tab[t*16+f] = {cos, sin}
    int i = bid * 256 + threadIdx.x;
    int tpos = i >> 4, f = i & 15;
    float ang = (float)tpos * exp2f(-(float)f * 0.83048202372184058696f);
    float s, c;
    sincosf(ang, &s, &c);
    tab[i * 2] = c;
    tab[i * 2 + 1] = s;
    return;
  }
  bid -= 128;
  const float* in;
  u16* out;
  if (bid < 4096) { in = x; out = xb; }
  else if (bid < 7168) { bid -= 4096; in = qkv_w; out = wqkv; }
  else { bid -= 7168; in = out_w; out = wout; }
  int i = bid * 256 + threadIdx.x;
  float4 v = ((const float4*)in)[i];
  uint2 o;
  o.x = (unsigned)f2bf(v.x) | ((unsigned)f2bf(v.y) << 16);
  o.y = (unsigned)f2bf(v.z) | ((unsigned)f2bf(v.w) << 16);
  ((uint2*)out)[i] = o;
}

// ---------------- gemm_qkv: x@W^T + b, fused RoPE + scatter to Q/K/Vt ----------------
// A:[M][1024] bf16 (x), Bt:[3072][1024] bf16 (qkv_w). 128x128 tile, BK=32, 4 waves 2x2.
// Epilogue: region = q/k/v by column; rope in fp32 via shfl_xor pair; writes:
//   q -> Q[(b*16+h)*T+t][d] (scaled 0.125*log2e), k -> K[...], v -> Vt[(b*16+h)*64+d][t].
__global__ __launch_bounds__(256) void gemm_qkv(const u16* __restrict__ A,
    const u16* __restrict__ Bt, const float* __restrict__ bias, const float* __restrict__ tab,
    u16* __restrict__ Q, u16* __restrict__ K, u16* __restrict__ Vt)
{
  __shared__ u16 lsA[2][128 * 32];
  __shared__ u16 lsB[2][128 * 32];
  const int t = threadIdx.x;
  const int l = t & 63, w = t >> 6;
  const int wm = (w >> 1) * 64, wn = (w & 1) * 64;
  const int lr = l & 15, lg = l >> 4;
  const long bm = (long)blockIdx.y * 128, bn = (long)blockIdx.x * 128;
  const int KD = HID;

  f32x4 acc[4][4];
#pragma unroll
  for (int i = 0; i < 4; i++)
#pragma unroll
    for (int j = 0; j < 4; j++) acc[i][j] = (f32x4){0.f, 0.f, 0.f, 0.f};

  const int srow = l >> 2, sko = (l & 3) * 8;
  const u16* Ab = A + (bm + srow) * (long)KD + sko;
  const u16* Bb = Bt + (bn + srow) * (long)KD + sko;

  auto stage = [&](int buf, int k0) {
#pragma unroll
    for (int g = 0; g < 2; g++)
      gload16(Ab + (long)((w * 2 + g) * 16) * KD + k0, &lsA[buf][(w * 2 + g) * 512]);
#pragma unroll
    for (int g = 0; g < 2; g++)
      gload16(Bb + (long)((w * 2 + g) * 16) * KD + k0, &lsB[buf][(w * 2 + g) * 512]);
  };

  stage(0, 0);
  __syncthreads();  // drains vmcnt(0): tile 0 landed
  int cur = 0;
  for (int k0 = 0; k0 < KD; k0 += 32) {
    if (k0 + 32 < KD) stage(cur ^ 1, k0 + 32);  // prefetch overlaps compute below
    bf16x8 af[4], bfv[4];
#pragma unroll
    for (int mi = 0; mi < 4; mi++)
      af[mi] = *(const bf16x8*)&lsA[cur][(wm + mi * 16 + lr) * 32 + lg * 8];
#pragma unroll
    for (int ni = 0; ni < 4; ni++)
      bfv[ni] = *(const bf16x8*)&lsB[cur][(wn + ni * 16 + lr) * 32 + lg * 8];
    __builtin_amdgcn_s_setprio(1);
#pragma unroll
    for (int mi = 0; mi < 4; mi++)
#pragma unroll
      for (int ni = 0; ni < 4; ni++)
        acc[mi][ni] = __builtin_amdgcn_mfma_f32_16x16x32_bf16(af[mi], bfv[ni], acc[mi][ni], 0, 0, 0);
    __builtin_amdgcn_s_setprio(0);
    __syncthreads();  // vmcnt(0)+barrier: prefetch landed, reads done before overwrite
    cur ^= 1;
  }

  // ---- fused epilogue ----
  const int region = (int)(bn >> 10);                 // 0=q, 1=k, 2=v (block-uniform)
  const int h = (int)(((bn + wn) & 1023) >> 6);       // wave's 64-col strip = one head
  const float2* tab2 = (const float2*)tab;
  u16* QK = (region == 0) ? Q : K;

#pragma unroll
  for (int mi = 0; mi < 4; mi++) {
    const int m0 = (int)(bm) + wm + mi * 16 + lg * 4;  // rows m0..m0+3 (same b)
    const int b = m0 >> 11, t0 = m0 & (T_ - 1);
    const long bh = b * 16 + h;
#pragma unroll
    for (int ni = 0; ni < 4; ni++) {
      const int d = ni * 16 + lr;
      const long col = bn + wn + d;
      const float bv = bias[col];
      float vv[4];
#pragma unroll
      for (int r = 0; r < 4; r++) vv[r] = acc[mi][ni][r] + bv;
      if (region < 2 && ni < 2) {  // rope on d<32
        const int fi = d >> 1;
        const float sgn = (d & 1) ? 1.f : -1.f;
#pragma unroll
        for (int r = 0; r < 4; r++) {
          float pvv = __shfl_xor(vv[r], 1, 64);
          float2 cs = tab2[(t0 + r) * 16 + fi];
          vv[r] = vv[r] * cs.x + sgn * pvv * cs.y;
        }
      }
      if (region == 0) {
#pragma unroll
        for (int r = 0; r < 4; r++) vv[r] *= SCALE_Q;
      }
      if (region < 2) {
#pragma unroll
        for (int r = 0; r < 4; r++)
          QK[(bh * T_ + t0 + r) * 64 + d] = f2bf(vv[r]);
      } else {
        uint2 pk;
        pk.x = cvt_pk_bf16(vv[0], vv[1]);
        pk.y = cvt_pk_bf16(vv[2], vv[3]);
        *(uint2*)&Vt[(bh * 64 + d) * (long)T_ + t0] = pk;
      }
    }
  }
}

// ---------------- NT GEMM (out-proj): C = A.Bt^T + bias, fp32 out ----------------
// A:[M][K], Bt:[N][K] bf16. Tile 64 x 128, BK=32, 4 waves 1x4.
__global__ __launch_bounds__(256) void gemm_out(const u16* __restrict__ A,
    const u16* __restrict__ Bt, const float* __restrict__ bias,
    float* __restrict__ outp, int N, int K)
{
  constexpr int BM = 64;
  constexpr int MI = 4, NI = 2;
  __shared__ u16 lsA[2][BM * 32];
  __shared__ u16 lsB[2][128 * 32];
  const int t = threadIdx.x;
  const int l = t & 63, w = t >> 6;
  const int wn = w * 32;
  const int lr = l & 15, lg = l >> 4;
  const long bm = (long)blockIdx.y * BM, bn = (long)blockIdx.x * 128;

  f32x4 acc[MI][NI];
#pragma unroll
  for (int i = 0; i < MI; i++)
#pragma unroll
    for (int j = 0; j < NI; j++) acc[i][j] = (f32x4){0.f, 0.f, 0.f, 0.f};

  const int srow = l >> 2, sko = (l & 3) * 8;
  const u16* Ab = A + (bm + srow) * (long)K + sko;
  const u16* Bb = Bt + (bn + srow) * (long)K + sko;

  auto stage = [&](int buf, int k0) {
    gload16(Ab + (long)(w * 16) * K + k0, &lsA[buf][w * 512]);
    gload16(Bb + (long)(w * 16) * K + k0, &lsB[buf][w * 512]);
    gload16(Bb + (long)((w + 4) * 16) * K + k0, &lsB[buf][(w + 4) * 512]);
  };

  stage(0, 0);
  __syncthreads();
  int cur = 0;
  for (int k0 = 0; k0 < K; k0 += 32) {
    if (k0 + 32 < K) stage(cur ^ 1, k0 + 32);
    bf16x8 af[MI], bfv[NI];
#pragma unroll
    for (int mi = 0; mi < MI; mi++)
      af[mi] = *(const bf16x8*)&lsA[cur][(mi * 16 + lr) * 32 + lg * 8];
#pragma unroll
    for (int ni = 0; ni < NI; ni++)
      bfv[ni] = *(const bf16x8*)&lsB[cur][(wn + ni * 16 + lr) * 32 + lg * 8];
    __builtin_amdgcn_s_setprio(1);
#pragma unroll
    for (int mi = 0; mi < MI; mi++)
#pragma unroll
      for (int ni = 0; ni < NI; ni++)
        acc[mi][ni] = __builtin_amdgcn_mfma_f32_16x16x32_bf16(af[mi], bfv[ni], acc[mi][ni], 0, 0, 0);
    __builtin_amdgcn_s_setprio(0);
    __syncthreads();
    cur ^= 1;
  }
#pragma unroll
  for (int mi = 0; mi < MI; mi++)
#pragma unroll
    for (int ni = 0; ni < NI; ni++) {
      long row = bm + mi * 16 + lg * 4;
      long col = bn + wn + ni * 16 + lr;
      float bv = bias[col];
#pragma unroll
      for (int r = 0; r < 4; r++)
        outp[(row + r) * (long)N + col] = acc[mi][ni][r] + bv;
    }
}

// ---------------- causal flash attention, swapped-QK^T, dbuf prefetch (R3-verbatim) ----
// 1024 blocks (heavy qt first), 4 waves; wave w owns q-rows [qt*64+w*16, +16).
__global__ __launch_bounds__(256, 4) void fattn(const u16* __restrict__ Q, const u16* __restrict__ Kp,
                                                const u16* __restrict__ V, u16* __restrict__ O) {
  const int id = blockIdx.x;
  const int qt = 31 - (id >> 5);  // heavy blocks dispatched first
  const int bh = id & 31;
  __shared__ u16 lsK[2][64 * 64];  // [krow][d], XOR swizzle: u16 chunk ^= (row&7)
  __shared__ u16 lsV[2][64 * 64];  // [d][k], same swizzle
  __shared__ u32 lsP[4][16 * 36];  // per-wave P round-trip
  const int t = threadIdx.x, l = t & 63, w = t >> 6;
  const int lr = l & 15, lg = l >> 4;
  const u16* Qb = Q + (long)bh * T_ * 64;
  const u16* Kb = Kp + (long)bh * T_ * 64;
  const u16* Vb = V + (long)bh * 64 * T_;
  u32* lsPw = lsP[w];

  bf16x8 aq[2];  // B-frag: Q rows (pre-scaled by 0.125*log2e)
#pragma unroll
  for (int ks = 0; ks < 2; ks++)
    aq[ks] = *(const bf16x8*)&Qb[((long)(qt * 64 + w * 16 + lr)) * 64 + ks * 32 + lg * 8];

  f32x4 o[4];
#pragma unroll
  for (int di = 0; di < 4; di++) o[di] = (f32x4){0.f, 0.f, 0.f, 0.f};
  float mrow = -1e30f, lrow = 0.f;

  // staging: slab = 8 rows x 128B; wave w stages slabs {2w,2w+1} of K and V.
  // pre-swizzled global source (m173): LDS chunk c holds src chunk c^(row&7).
  const int srow = l >> 3;
  const int scx = ((l & 7) ^ srow) * 8;
  const long kgo0 = (long)(16 * w + srow) * 64 + scx;
  const long kgo1 = (long)(16 * w + 8 + srow) * 64 + scx;
  const long vgo0 = (long)(16 * w + srow) * T_ + scx;
  const long vgo1 = (long)(16 * w + 8 + srow) * T_ + scx;

  gload16(Kb + kgo0, &lsK[0][(2 * w) * 512]);
  gload16(Kb + kgo1, &lsK[0][(2 * w + 1) * 512]);
  gload16(Vb + vgo0, &lsV[0][(2 * w) * 512]);
  gload16(Vb + vgo1, &lsV[0][(2 * w + 1) * 512]);
  __syncthreads();  // vmcnt(0) drain: tile 0 ready

  int cur = 0;
  for (int kt = 0; kt <= qt; kt++) {
    if (kt < qt) {  // prefetch next tile; lands by the end-of-iter barrier
      const u16* kp = Kb + (kt + 1) * 4096;
      const u16* vp = Vb + (kt + 1) * 64;
      gload16(kp + kgo0, &lsK[cur ^ 1][(2 * w) * 512]);
      gload16(kp + kgo1, &lsK[cur ^ 1][(2 * w + 1) * 512]);
      gload16(vp + vgo0, &lsV[cur ^ 1][(2 * w) * 512]);
      gload16(vp + vgo1, &lsV[cur ^ 1][(2 * w + 1) * 512]);
    }

    // S^T = K . Q^T : s[ji] rows k=ji*16+lg*4+r, col q=lr
    f32x4 s[4];
#pragma unroll
    for (int ji = 0; ji < 4; ji++) s[ji] = (f32x4){0.f, 0.f, 0.f, 0.f};
    __builtin_amdgcn_s_setprio(1);
#pragma unroll
    for (int ks = 0; ks < 2; ks++)
#pragma unroll
      for (int ji = 0; ji < 4; ji++) {
        int row = ji * 16 + lr;
        bf16x8 kf = *(const bf16x8*)&lsK[cur][row * 64 + ((ks * 32 + lg * 8) ^ ((row & 7) * 8))];
        s[ji] = __builtin_amdgcn_mfma_f32_16x16x32_bf16(kf, aq[ks], s[ji], 0, 0, 0);
      }
    __builtin_amdgcn_s_setprio(0);

    if (kt == qt) {  // diagonal tile only
      int qloc = w * 16 + lr;
#pragma unroll
      for (int ji = 0; ji < 4; ji++)
#pragma unroll
        for (int r = 0; r < 4; r++)
          if (ji * 16 + lg * 4 + r > qloc) s[ji][r] = -1e30f;
    }

    float mx = s[0][0];
#pragma unroll
    for (int ji = 0; ji < 4; ji++)
#pragma unroll
      for (int r = 0; r < 4; r++) mx = fmaxf(mx, s[ji][r]);
    mx = fmaxf(mx, __shfl_xor(mx, 16, 64));
    mx = fmaxf(mx, __shfl_xor(mx, 32, 64));

    if (__any(mx - mrow > 8.f)) {  // defer-max (T13): rescale only on real growth
      float newm = fmaxf(mrow, mx);
      float sf = fexp2(mrow - newm);
      mrow = newm;
      lrow *= sf;
#pragma unroll
      for (int r = 0; r < 4; r++) {
        float sfb = __shfl(sf, lg * 4 + r, 64);
#pragma unroll
        for (int di = 0; di < 4; di++) o[di][r] *= sfb;
      }
    }

    float rs = 0.f;
    u32 pd[8];
#pragma unroll
    for (int ji = 0; ji < 4; ji++)
#pragma unroll
      for (int hh = 0; hh < 2; hh++) {
        float p0 = fexp2(s[ji][2 * hh] - mrow);
        float p1 = fexp2(s[ji][2 * hh + 1] - mrow);
        rs += p0 + p1;
        pd[ji * 2 + hh] = cvt_pk_bf16(p0, p1);
      }
    rs += __shfl_xor(rs, 16, 64);
    rs += __shfl_xor(rs, 32, 64);
    lrow += rs;

    // P -> per-wave LDS (packed b64 stores), read back as PV A-frags
#pragma unroll
    for (int ji = 0; ji < 4; ji++)
      *(uint2*)&lsPw[lr * 36 + ji * 8 + lg * 2] = make_uint2(pd[2 * ji], pd[2 * ji + 1]);
    __builtin_amdgcn_s_setprio(1);
#pragma unroll
    for (int js = 0; js < 2; js++) {
      bf16x8 pa = *(const bf16x8*)&lsPw[lr * 36 + js * 16 + lg * 4];
#pragma unroll
      for (int di = 0; di < 4; di++) {
        int drow = di * 16 + lr;
        bf16x8 vb = *(const bf16x8*)&lsV[cur][drow * 64 + ((js * 32 + lg * 8) ^ ((drow & 7) * 8))];
        o[di] = __builtin_amdgcn_mfma_f32_16x16x32_bf16(pa, vb, o[di], 0, 0, 0);
      }
    }
    __builtin_amdgcn_s_setprio(0);

    if (kt < qt) __syncthreads();  // drain prefetch + guard buffer reuse
    cur ^= 1;
  }

  const int b = bh >> 4, h = bh & 15;
  float inv = 1.f / lrow;
#pragma unroll
  for (int r = 0; r < 4; r++) {
    float invb = __shfl(inv, lg * 4 + r, 64);
#pragma unroll
    for (int di = 0; di < 4; di++) {
      long rowt = (long)(b * T_ + qt * 64 + w * 16 + lg * 4 + r);
      O[rowt * 1024 + h * 64 + di * 16 + lr] = f2bf(o[di][r] * invb);
    }
  }
}

extern "C" void kernel_launch(void* const* d_in, const int* in_sizes, int n_in,
                              void* d_out, int out_size, void* d_ws, size_t ws_size,
                              hipStream_t stream) {
  (void)in_sizes; (void)n_in; (void)out_size; (void)ws_size;
  const float* x     = (const float*)d_in[0];
  // d_in[1] = mask: deterministic causal triu — applied analytically, not read.
  const float* qkv_w = (const float*)d_in[2];
  const float* qkv_b = (const float*)d_in[3];
  const float* out_w = (const float*)d_in[4];
  const float* out_b = (const float*)d_in[5];
  char* ws = (char*)d_ws;
  size_t off = 0;
  auto alloc = [&](size_t n) { void* p = ws + off; off += (n + 255) & ~(size_t)255; return p; };
  u16*   xb    = (u16*)alloc((size_t)M_ * HID * 2);
  u16*   wqkv  = (u16*)alloc((size_t)NQKV * HID * 2);
  u16*   wout  = (u16*)alloc((size_t)HID * HID * 2);
  u16*   Qb    = (u16*)alloc((size_t)M_ * HID * 2);
  u16*   Kb    = (u16*)alloc((size_t)M_ * HID * 2);
  u16*   Vtb   = (u16*)alloc((size_t)M_ * HID * 2);
  u16*   attnb = (u16*)alloc((size_t)M_ * HID * 2);
  float* tab   = (float*)alloc((size_t)T_ * 16 * 2 * 4);

  prep<<<8320, 256, 0, stream>>>(x, qkv_w, out_w, xb, wqkv, wout, tab);
  gemm_qkv<<<dim3(NQKV / 128, M_ / 128), 256, 0, stream>>>(xb, wqkv, qkv_b, tab, Qb, Kb, Vtb);
  fattn<<<1024, 256, 0, stream>>>(Qb, Kb, Vtb, attnb);
  gemm_out<<<dim3(HID / 128, M_ / 64), 256, 0, stream>>>(attnb, wout, out_b, (float*)d_out, HID, HID);
}